// Round 5
// baseline (98.275 us; speedup 1.0000x reference)
//
#include <hip/hip_runtime.h>
#include <math.h>

#define NEL   4096
#define NT    1024
#define HALF  512            // threads per array half (sorted-range ownership)
#define EPT   8              // sorted elements per half-thread
#define CPT   4              // original indices per thread (both arrays)
#define NPROD 128            // producer blocks
#define JLEN  256            // j-segment length per producer
// non-repeated-byte magics: can never equal a single-byte-pattern poison
#define MAGICZ 0x13579BDFu
#define MAGICP 0x2468ACE1u

// wave-synchronous LDS fence (lanes lockstep; drains own wave's ds ops)
#define WSYNC() asm volatile("s_waitcnt lgkmcnt(0)" ::: "memory")

// ---------------------------------------------------------------------------
// single-boundary pool merge of adjacent isotonic regions [lo,mid),[mid,hi)
// invariant: block [a,b] has C[a] == C[b] == b-a+1
// ---------------------------------------------------------------------------
__device__ inline void pav_merge(double* P, int* C, const int lo, const int mid,
                                 const int hi) {
  const int llen = C[mid - 1];
  int cs = mid - llen;
  const int rlen = C[mid];
  int ce = mid + rlen - 1;
  const double mL = (P[mid] - P[cs]) / (double)llen;
  const double mR = (P[ce + 1] - P[mid]) / (double)rlen;
  if (mL <= mR) {                        // boundary violation -> pool
    double mu = (P[ce + 1] - P[cs]) / (double)(ce - cs + 1);
    bool changed = true;
    while (changed) {
      changed = false;
      while (cs > lo) {
        const int l2 = C[cs - 1];
        const double m2 = (P[cs] - P[cs - l2]) / (double)l2;
        if (m2 <= mu) {
          cs -= l2;
          mu = (P[ce + 1] - P[cs]) / (double)(ce - cs + 1);
          changed = true;
        } else break;
      }
      while (ce < hi - 1) {
        const int l2 = C[ce + 1];
        const double m2 = (P[ce + 1 + l2] - P[ce + 1]) / (double)l2;
        if (m2 >= mu) {
          ce += l2;
          mu = (P[ce + 1] - P[cs]) / (double)(ce - cs + 1);
          changed = true;
        } else break;
      }
    }
    const int len = ce - cs + 1;
    C[cs] = len;
    C[ce] = len;
  }
}

// ---------------------------------------------------------------------------
// ONE kernel, 129 blocks x 1024 threads (all co-resident: 1 block/CU).
// block 0 = consumer (zero counts -> release zflag -> spin dflags -> PAV+loss)
// blocks 1..128 = producers (count 256-j segment -> spin zflag -> atomicAdd
//                            -> release own dflag)
// ws layout: counts (2*4096 u32 = 32 KB) | dflags (128 u32) | zflag (1 u32)
// ---------------------------------------------------------------------------
__global__ __launch_bounds__(NT, 1)
void spearman_kernel(const float* __restrict__ pred,
                     const float* __restrict__ target,
                     unsigned int* __restrict__ ws,
                     float* __restrict__ loss_out) {
  __shared__ float  s_val[2][NEL];      // sorted values; later sorted ranks
  __shared__ double s_P[2][NEL + 1];    // prefix sums of z
  __shared__ int    s_cnt[2][NEL];      // block stamps -> bstart list
  __shared__ double s_wsum[2][HALF / 64];
  __shared__ int    s_nb[2];
  __shared__ double s_red[NT / 64][5];

  unsigned int* counts = ws;                 // 2*NEL
  unsigned int* dflags = ws + 2 * NEL;       // NPROD
  unsigned int* zflag  = ws + 2 * NEL + NPROD;

  const int tid  = threadIdx.x;
  const int lane = tid & 63;
  const int wid  = tid >> 6;

  if (blockIdx.x != 0) {
    // =================== PRODUCER =========================================
    const int pid = blockIdx.x - 1;          // 0..127
    const int arr = pid >> 6;                // 0/1
    const int rem = pid & 63;
    const int ic  = rem >> 4;                // 0..3  (i-chunk of 1024)
    const int js  = rem & 15;                // 0..15 (j-seg of 256)
    const float* __restrict__ x = arr ? target : pred;
    const int i     = ic * NT + tid;
    const int jbase = js * JLEN;

    float* jv = s_val[0];                    // reuse LDS
    if (tid < JLEN) jv[tid] = x[jbase + tid];
    const float xi = x[i];
    __syncthreads();

    unsigned int c = 0;
    const float4* jv4 = (const float4*)jv;
#pragma unroll 8
    for (int t4 = 0; t4 < JLEN / 4; t4++) {
      const float4 v = jv4[t4];
      const int j = jbase + 4 * t4;
      c += (v.x > xi || (v.x == xi && j + 0 < i)) ? 1u : 0u;
      c += (v.y > xi || (v.y == xi && j + 1 < i)) ? 1u : 0u;
      c += (v.z > xi || (v.z == xi && j + 2 < i)) ? 1u : 0u;
      c += (v.w > xi || (v.w == xi && j + 3 < i)) ? 1u : 0u;
    }
    // wait until consumer has zeroed counts (compute overlapped the wait)
    while (__hip_atomic_load(zflag, __ATOMIC_ACQUIRE,
                             __HIP_MEMORY_SCOPE_AGENT) != MAGICZ)
      __builtin_amdgcn_s_sleep(1);
    atomicAdd(&counts[arr * NEL + i], c);    // device-scope, distinct addrs
    __syncthreads();
    if (tid == 0) {
      __threadfence();
      __hip_atomic_store(&dflags[pid], MAGICP, __ATOMIC_RELEASE,
                         __HIP_MEMORY_SCOPE_AGENT);
    }
    return;
  }

  // ===================== CONSUMER (block 0) ===============================
  // prefetch own values while zeroing
  const float4 xp = ((const float4*)pred)[tid];
  const float4 xt = ((const float4*)target)[tid];
  counts[tid]       = 0u;                    // zero 2*NEL counts
  counts[NT + tid]  = 0u;
  counts[2 * NT + tid] = 0u;
  counts[3 * NT + tid] = 0u;
  counts[4 * NT + tid] = 0u;
  counts[5 * NT + tid] = 0u;
  counts[6 * NT + tid] = 0u;
  counts[7 * NT + tid] = 0u;
  __syncthreads();                                   // B1
  if (tid == 0) {
    __threadfence();
    __hip_atomic_store(zflag, MAGICZ, __ATOMIC_RELEASE,
                       __HIP_MEMORY_SCOPE_AGENT);
  }
  // spin: thread t waits for producer t
  if (tid < NPROD) {
    while (__hip_atomic_load(&dflags[tid], __ATOMIC_ACQUIRE,
                             __HIP_MEMORY_SCOPE_AGENT) != MAGICP)
      __builtin_amdgcn_s_sleep(1);
    __threadfence();
  }
  __syncthreads();                                   // B2

  // ---- load final counts = sorted positions; scatter values -------------
  int rp[CPT], rt[CPT];
  {
    const int4 a = ((const int4*)counts)[tid];
    const int4 b = ((const int4*)counts)[NEL / 4 + tid];
    rp[0] = a.x; rp[1] = a.y; rp[2] = a.z; rp[3] = a.w;
    rt[0] = b.x; rt[1] = b.y; rt[2] = b.z; rt[3] = b.w;
    s_val[0][rp[0]] = xp.x; s_val[0][rp[1]] = xp.y;
    s_val[0][rp[2]] = xp.z; s_val[0][rp[3]] = xp.w;
    s_val[1][rt[0]] = xt.x; s_val[1][rt[1]] = xt.y;
    s_val[1][rt[2]] = xt.z; s_val[1][rt[3]] = xt.w;
  }
  __syncthreads();                                   // B3

  // ---- sorted-range ownership --------------------------------------------
  const int arr = tid >> 9;            // 0: pred, 1: target
  const int tA  = tid & (HALF - 1);
  const int wA  = tA >> 6;             // wave within half, 0..7
  const int b0  = tA * EPT;
  double* P = s_P[arr];
  int*    C = s_cnt[arr];

  // ---- register prefix of z_p = s_p - (NEL - p) over own 8 elements ------
  double c[EPT];
  {
    double acc = 0.0;
#pragma unroll
    for (int e = 0; e < EPT; e++) {
      const int p = b0 + e;
      acc += (double)s_val[arr][p] - (double)(NEL - p);
      c[e] = acc;
    }
  }
  const double tot = c[EPT - 1];
  double sc = tot;
#pragma unroll
  for (int d = 1; d < 64; d <<= 1) {
    const double o = __shfl_up(sc, d, 64);
    if (lane >= d) sc += o;
  }
  if (lane == 63) s_wsum[arr][wA] = sc;
  __syncthreads();                                   // B4
  double wexcl = 0.0;
#pragma unroll
  for (int w = 0; w < HALF / 64; w++)
    wexcl += (w < wA) ? s_wsum[arr][w] : 0.0;
  const double excl = wexcl + (sc - tot);            // == P[b0]
#pragma unroll
  for (int e = 0; e < EPT; e++) P[b0 + 1 + e] = excl + c[e];
  if (lane == 0) P[b0] = excl;

  // ---- serial left-to-right PAV on own range [b0, b0+8): no sync ---------
  C[b0] = 1;
  for (int p = b0 + 1; p < b0 + EPT; p++) {
    int cs = p;
    const double Pe = P[p + 1];
    while (cs > b0) {
      const int l2 = C[cs - 1];
      const int lb = cs - l2;
      const double Pcs = P[cs];
      const double Plb = (lb == b0) ? excl : P[lb];
      const double mPrev = (Pcs - Plb) / (double)l2;
      const double mCur  = (Pe - Pcs) / (double)(p - cs + 1);
      if (mPrev <= mCur) cs = lb; else break;
    }
    C[cs] = p - cs + 1;
    C[p]  = p - cs + 1;
  }
  WSYNC();

  // ---- within-wave levels m = 8..256 (spans 16..512), wave-synchronous ---
  const int wbase = wA * 512;
#pragma unroll
  for (int m = EPT; m <= 256; m <<= 1) {
    const int nm = 512 / (2 * m);
    if (lane < nm) {
      const int lo = wbase + lane * 2 * m;
      pav_merge(P, C, lo, lo + m, lo + 2 * m);
    }
    WSYNC();
  }
  __syncthreads();                                   // B5

  // ---- cross-wave levels m = 512..2048 + walk: first wave per half -------
  if (wA == 0) {
#pragma unroll
    for (int m = 512; m <= 2048; m <<= 1) {
      const int nm = NEL / (2 * m);
      if (lane < nm) {
        const int lo = lane * 2 * m;
        pav_merge(P, C, lo, lo + m, lo + 2 * m);
      }
      WSYNC();
    }
    if (lane == 0) {                   // walk block list -> bstart (aliased)
      int s = 0, b = 0;
      while (s < NEL) {
        const int cc = C[s];           // read BEFORE aliased write
        C[b] = s;
        b++;
        s += cc;
      }
      s_nb[arr] = b;
    }
  }
  __syncthreads();                                   // B6

  // ---- rank at own sorted positions, in place ----------------------------
  const int nb = s_nb[arr];
#pragma unroll
  for (int e = 0; e < EPT; e++) {
    const int p = b0 + e;
    int lo = 0, hi = nb - 1;
    while (lo < hi) {
      const int md = (lo + hi + 1) >> 1;
      if (C[md] <= p) lo = md; else hi = md - 1;
    }
    const int st = C[lo];
    const int en = (lo + 1 < nb) ? C[lo + 1] : NEL;
    const double v = (P[en] - P[st]) / (double)(en - st);
    s_val[arr][p] = (float)((double)s_val[arr][p] - v);
  }
  __syncthreads();                                   // B7

  // ---- Pearson loss: gather both rank vectors via rp/rt ------------------
  double Sp = 0.0, Sq = 0.0, Spp = 0.0, Sqq = 0.0, Spq = 0.0;
#pragma unroll
  for (int e = 0; e < CPT; e++) {
    const double p = (double)s_val[0][rp[e]];
    const double q = (double)s_val[1][rt[e]];
    Sp += p; Sq += q; Spp += p * p; Sqq += q * q; Spq += p * q;
  }
#pragma unroll
  for (int d = 32; d > 0; d >>= 1) {
    Sp  += __shfl_down(Sp,  d, 64);
    Sq  += __shfl_down(Sq,  d, 64);
    Spp += __shfl_down(Spp, d, 64);
    Sqq += __shfl_down(Sqq, d, 64);
    Spq += __shfl_down(Spq, d, 64);
  }
  if (lane == 0) {
    s_red[wid][0] = Sp;  s_red[wid][1] = Sq;  s_red[wid][2] = Spp;
    s_red[wid][3] = Sqq; s_red[wid][4] = Spq;
  }
  __syncthreads();                                   // B8
  if (tid == 0) {
    double a0 = 0, a1 = 0, a2 = 0, a3 = 0, a4 = 0;
    for (int w = 0; w < NT / 64; w++) {
      a0 += s_red[w][0]; a1 += s_red[w][1]; a2 += s_red[w][2];
      a3 += s_red[w][3]; a4 += s_red[w][4];
    }
    const double n  = (double)NEL;
    const double mp = a0 / n, mq = a1 / n;
    const double cov = a4 - n * mp * mq;
    const double vp  = a2 - n * mp * mp;
    const double vq  = a3 - n * mq * mq;
    loss_out[0] = (float)(1.0 - cov / sqrt(vp * vq));
  }
}

// ---------------------------------------------------------------------------
extern "C" void kernel_launch(void* const* d_in, const int* in_sizes, int n_in,
                              void* d_out, int out_size, void* d_ws, size_t ws_size,
                              hipStream_t stream) {
  const float* pred   = (const float*)d_in[0];
  const float* target = (const float*)d_in[1];
  unsigned int* ws = (unsigned int*)d_ws;  // counts | dflags | zflag (~33 KB)
  float* out = (float*)d_out;

  hipLaunchKernelGGL(spearman_kernel, dim3(NPROD + 1), dim3(NT), 0, stream,
                     pred, target, ws, out);
}